// Round 18
// baseline (43.284 us; speedup 1.0000x reference)
//
#include <hip/hip_runtime.h>
#include <cstddef>

#define T_DIM 30000
#define M_DIM 23
#define NJ    92
#define TILE  64       // output timesteps per conv block
#define SUBS  25       // sub LDS stride
#define XP4   377      // reduce LDS pitch in float4
#define PADC  50       // leading pad (ushorts) per Ycp column
#define CSTR  30208    // Ycp column stride in ushorts (60416 B)
#define CSTR32 (CSTR/2)

typedef short bf16x8 __attribute__((ext_vector_type(8)));
typedef float f32x4  __attribute__((ext_vector_type(4)));

__device__ __forceinline__ unsigned short f2bf(float f) {
    unsigned int u = __float_as_uint(f);
    return (unsigned short)((u + 0x7fffu + ((u >> 16) & 1u)) >> 16);
}

// ---- Kernel B: X (T,1500) fp32 -> Ycp (92 cols x CSTR) bf16 column-major.
// High-TLP (2 rows / 128-thread block) + tiny LDS transpose + XCD-swizzled
// t-mapping. Pads zeroed by blocks 0..91. Block 0 also writes the Toeplitz
// A-fragment table (16 frags x 64 lanes x 16B).
__global__ __launch_bounds__(128) void reduce_t(const float* __restrict__ X,
                                                const float* __restrict__ Tau,
                                                const float* __restrict__ Delta,
                                                const float* __restrict__ W,
                                                unsigned short* __restrict__ Ycp,
                                                unsigned int* __restrict__ afrag) {
    __shared__ __align__(16) float4 Xs[2 * XP4];          // 12064 B
    __shared__ unsigned short Ytr[92 * 2];                // 368 B

    const int tid = threadIdx.x;
    const int b   = blockIdx.x;
    const int swb = (b & 7) * 1875 + (b >> 3);            // XCD-contiguous t ranges
    const int tb  = swb * 2;

    const float4* Xg = reinterpret_cast<const float4*>(X) + (size_t)tb * 375;
    #pragma unroll
    for (int it = 0; it < 6; ++it) {
        int i = tid + 128 * it;
        if (i < 750) {
            int r = (i >= 375) ? 1 : 0;
            int pos = i - r * 375;
            Xs[r * XP4 + pos] = Xg[i];
        }
    }
    __syncthreads();

    if (tid < 46) {
        int r = tid / 23;
        int q = tid - 23 * r;
        const float4* row = &Xs[r * XP4];
        float4 s = make_float4(0.f, 0.f, 0.f, 0.f);
        #pragma unroll
        for (int k = 0; k < 16; ++k) {
            float4 v = row[q + 23 * k];
            s.x += v.x; s.y += v.y; s.z += v.z; s.w += v.w;
        }
        if (q < 7) {
            float4 v = row[q + 23 * 16];
            s.x += v.x; s.y += v.y; s.z += v.z; s.w += v.w;
        }
        Ytr[(4 * q + 0) * 2 + r] = f2bf(s.x);
        Ytr[(4 * q + 1) * 2 + r] = f2bf(s.y);
        Ytr[(4 * q + 2) * 2 + r] = f2bf(s.z);
        Ytr[(4 * q + 3) * 2 + r] = f2bf(s.w);
    }
    __syncthreads();

    if (tid < 92) {
        unsigned int v = (unsigned)Ytr[tid * 2] | ((unsigned)Ytr[tid * 2 + 1] << 16);
        reinterpret_cast<unsigned int*>(Ycp)[(size_t)tid * CSTR32 + (PADC + tb) / 2] = v;
    }

    // pad zeroing: block b (< 92) owns column b; 25 lead + 79 tail dwords
    if (b < 92 && tid < 104) {
        unsigned int* col32 = reinterpret_cast<unsigned int*>(Ycp) + (size_t)b * CSTR32;
        int u = (tid < 25) ? tid : (15025 + (tid - 25));
        col32[u] = 0u;
    }

    // block 0: Toeplitz A-fragments. A_g[i,k] = Wpad_g[k-i]; frag (g,kk):
    // lane l elem j -> i = l&15, k = kk*32 + (l>>4)*8 + j; x = k - i.
    if (b == 0) {
        for (int item = tid; item < 1024; item += 128) {
            int f = item >> 6;
            int l = item & 63;
            int g = f >> 2, kk = f & 3;
            float eD  = __expf(Delta[0]);
            float tau = __expf(Tau[g]);
            float wg  = W[g];
            unsigned short vals[8];
            #pragma unroll
            for (int j = 0; j < 8; ++j) {
                int x = kk * 32 + ((l >> 4) << 3) + j - (l & 15);
                float val = 0.f;
                if (x >= 0 && x <= 100) {
                    float tt  = fmaxf((float)x - eD, 0.f);
                    float tf  = tt / tau;
                    float fast = tf * __expf(-tf);
                    float kv;
                    if (g < 2) {
                        float ts = tt / (tau * 2.8f + 10.4f);
                        kv = (fast + ts * __expf(-ts) * 0.3f) * (1.0f / 1.3f);
                    } else {
                        kv = fast;
                    }
                    val = kv * wg;
                }
                vals[j] = f2bf(val);
            }
            uint4 o;
            o.x = (unsigned)vals[0] | ((unsigned)vals[1] << 16);
            o.y = (unsigned)vals[2] | ((unsigned)vals[3] << 16);
            o.z = (unsigned)vals[4] | ((unsigned)vals[5] << 16);
            o.w = (unsigned)vals[6] | ((unsigned)vals[7] << 16);
            reinterpret_cast<uint4*>(afrag)[f * 64 + l] = o;
        }
    }
}

// ---- Kernel C: MFMA Toeplitz conv + tree; no LDS staging. B-fragments direct
// from column-major Ycp (L2/L3-resident), A-fragments from global table.
__global__ __launch_bounds__(512, 4) void conv_tree_k(
    const unsigned short* __restrict__ Ycp,
    const unsigned int* __restrict__ afrag,
    const float* __restrict__ Vo,
    const float* __restrict__ C,
    const float* __restrict__ Theta,
    float* __restrict__ out)
{
    __shared__ float sub[TILE * SUBS];               // 6400 B
    __shared__ float sTheta[M_DIM];
    __shared__ float sExpC[M_DIM];

    const int tid = threadIdx.x;
    const int t0  = blockIdx.x * TILE;
    const int l   = tid & 63;

    if (tid < M_DIM) {
        sTheta[tid] = Theta[tid];
        sExpC[tid]  = __expf(C[tid]);
    }

    const int wave = tid >> 6;            // 0..7
    const int dt   = (wave & 3) * 16;     // t-subtile
    const int nt   = wave >> 2;           // m-tile (0: m 0-15, 1: m 16-22)
    const int n    = l & 15;
    const int m    = nt * 16 + n;
    const bool mvalid = (m < M_DIM);
    const int mc   = mvalid ? m : 0;
    const int kq   = (l >> 4) << 3;       // k-slot base: 0,8,16,24

    const uint4* AF = reinterpret_cast<const uint4*>(afrag);

    f32x4 acc = {0.f, 0.f, 0.f, 0.f};
    #pragma unroll
    for (int g = 0; g < 4; ++g) {
        // column j: j%23 == mc, j%4 == g -> a = 3*(g-mc) mod 4; j = mc + 23a
        int a  = (3 * ((g - mc) & 3)) & 3;
        int j  = mc + 23 * a;
        const unsigned short* colp = Ycp + (size_t)j * CSTR + t0 + dt + kq;

        uint4 a0 = AF[(g * 4 + 0) * 64 + l];
        uint4 a1 = AF[(g * 4 + 1) * 64 + l];
        uint4 a2 = AF[(g * 4 + 2) * 64 + l];
        uint4 a3 = AF[(g * 4 + 3) * 64 + l];

        bf16x8 b0 = *reinterpret_cast<const bf16x8*>(colp);
        acc = __builtin_amdgcn_mfma_f32_16x16x32_bf16(__builtin_bit_cast(bf16x8, a0), b0, acc, 0, 0, 0);
        bf16x8 b1 = *reinterpret_cast<const bf16x8*>(colp + 32);
        acc = __builtin_amdgcn_mfma_f32_16x16x32_bf16(__builtin_bit_cast(bf16x8, a1), b1, acc, 0, 0, 0);
        bf16x8 b2 = *reinterpret_cast<const bf16x8*>(colp + 64);
        acc = __builtin_amdgcn_mfma_f32_16x16x32_bf16(__builtin_bit_cast(bf16x8, a2), b2, acc, 0, 0, 0);
        bf16x8 b3 = *reinterpret_cast<const bf16x8*>(colp + 96);
        acc = __builtin_amdgcn_mfma_f32_16x16x32_bf16(__builtin_bit_cast(bf16x8, a3), b3, acc, 0, 0, 0);
    }

    // epilogue: D col = l&15 (m), row = (l>>4)*4 + r -> t_local = dt + row
    if (mvalid) {
        int i0 = (l >> 4) * 4;
        #pragma unroll
        for (int r = 0; r < 4; ++r)
            sub[(dt + i0 + r) * SUBS + m] = acc[r];
    }
    __syncthreads();

    // --- tree cascade, one thread per timestep
    if (tid < TILE) {
        int t = t0 + tid;
        if (t < T_DIM) {
            const float* s = &sub[tid * SUBS];
            float o[M_DIM];
            #pragma unroll
            for (int mm = 11; mm < 23; ++mm) {
                float x = s[mm] - sTheta[mm];
                o[mm] = sExpC[mm] / (1.f + __expf(-x));
            }
            #pragma unroll
            for (int rr = 10; rr >= 0; --rr) {
                float x = s[rr] + o[2 * rr + 1] + o[2 * rr + 2] - sTheta[rr];
                o[rr] = sExpC[rr] / (1.f + __expf(-x));
            }
            out[t] = o[0] + Vo[0];
        }
    }
}

extern "C" void kernel_launch(void* const* d_in, const int* in_sizes, int n_in,
                              void* d_out, int out_size, void* d_ws, size_t ws_size,
                              hipStream_t stream) {
    const float* X     = (const float*)d_in[0];
    const float* Vo    = (const float*)d_in[1];
    const float* Tau   = (const float*)d_in[2];
    const float* Delta = (const float*)d_in[3];
    const float* W     = (const float*)d_in[4];
    const float* C     = (const float*)d_in[5];
    const float* Theta = (const float*)d_in[6];
    float* out = (float*)d_out;

    unsigned short* Ycp = (unsigned short*)d_ws;                                   // 5.56 MB
    unsigned int* afrag = (unsigned int*)((char*)d_ws + (size_t)NJ * CSTR * 2);    // 16 KB

    reduce_t<<<T_DIM / 2, 128, 0, stream>>>(X, Tau, Delta, W, Ycp, afrag);
    conv_tree_k<<<469, 512, 0, stream>>>(Ycp, afrag, Vo, C, Theta, out);
}

// Round 19
// 38.696 us; speedup vs baseline: 1.1186x; 1.1186x over previous
//
#include <hip/hip_runtime.h>
#include <cstddef>

#define T_DIM 30000
#define M_DIM 23
#define NJ    92
#define TILE  64      // output timesteps per conv block
#define STR   184     // Yt stride in bf16 units (368 B)
#define SUBS  25      // sub LDS stride
#define ROWS  4       // rows per reduce block
#define NF4   1500    // float4 staged per reduce block (4 * 375), linear LDS

typedef short bf16x8 __attribute__((ext_vector_type(8)));
typedef float f32x4  __attribute__((ext_vector_type(4)));

__device__ __forceinline__ unsigned short f2bf(float f) {
    unsigned int u = __float_as_uint(f);
    return (unsigned short)((u + 0x7fffu + ((u >> 16) & 1u)) >> 16);
}

// ---- Kernel B: X (T,1500) fp32 -> Yb (T,92) bf16 ; Yb[t,j] = sum_{n%92==j} X[t,n]
// Staging via global_load_lds (width 16): no VGPR round-trip, no ds_writes.
// Linear LDS dest (wave-uniform base + lane*16). Block 0 also writes afrag.
__global__ __launch_bounds__(256) void reduce_k(const float* __restrict__ X,
                                                const float* __restrict__ Tau,
                                                const float* __restrict__ Delta,
                                                const float* __restrict__ W,
                                                unsigned short* __restrict__ Yb,
                                                unsigned int* __restrict__ afrag) {
    __shared__ __align__(16) float4 Xs[NF4];   // 24000 B, linear (no pad)

    const int tid  = threadIdx.x;
    const int lane = tid & 63;
    const int wid  = tid >> 6;
    const int tb   = blockIdx.x * ROWS;        // 7500 blocks x 4 rows

    const float4* Xg = reinterpret_cast<const float4*>(X) + (size_t)tb * 375;

    // phase A: DMA 1500 contiguous float4 into linear LDS
    #pragma unroll
    for (int it = 0; it < 6; ++it) {
        int base = it * 256 + wid * 64;        // wave-uniform LDS chunk base
        int i = base + lane;
        if (i < NF4) {
            __builtin_amdgcn_global_load_lds(
                (const __attribute__((address_space(1))) void*)(Xg + i),
                (__attribute__((address_space(3))) void*)(Xs + base),
                16, 0, 0);
        }
    }
    __syncthreads();

    // phase B: thread (r,q) sums float4s of row r at pos q + 23k
    if (tid < 92) {
        int r = tid / 23;
        int q = tid - 23 * r;
        const float4* row = &Xs[r * 375];
        float4 s = make_float4(0.f, 0.f, 0.f, 0.f);
        #pragma unroll
        for (int k = 0; k < 16; ++k) {
            float4 v = row[q + 23 * k];
            s.x += v.x; s.y += v.y; s.z += v.z; s.w += v.w;
        }
        if (q < 7) {
            float4 v = row[q + 23 * 16];
            s.x += v.x; s.y += v.y; s.z += v.z; s.w += v.w;
        }
        ushort4 o;
        o.x = f2bf(s.x); o.y = f2bf(s.y); o.z = f2bf(s.z); o.w = f2bf(s.w);
        reinterpret_cast<ushort4*>(Yb)[(size_t)(tb + r) * 23 + q] = o;
    }

    // block 0: Toeplitz A-fragments. A_g[i,k] = Wpad_g[k-i]; frag (g,kk):
    // lane l elem j -> i = l&15, k = kk*32 + (l>>4)*8 + j; x = k - i.
    if (blockIdx.x == 0) {
        for (int item = tid; item < 1024; item += 256) {
            int f = item >> 6;
            int l = item & 63;
            int g = f >> 2, kk = f & 3;
            float eD  = __expf(Delta[0]);
            float tau = __expf(Tau[g]);
            float wg  = W[g];
            unsigned short vals[8];
            #pragma unroll
            for (int j = 0; j < 8; ++j) {
                int x = kk * 32 + ((l >> 4) << 3) + j - (l & 15);
                float val = 0.f;
                if (x >= 0 && x <= 100) {
                    float tt  = fmaxf((float)x - eD, 0.f);
                    float tf  = tt / tau;
                    float fast = tf * __expf(-tf);
                    float kv;
                    if (g < 2) {
                        float ts = tt / (tau * 2.8f + 10.4f);
                        kv = (fast + ts * __expf(-ts) * 0.3f) * (1.0f / 1.3f);
                    } else {
                        kv = fast;
                    }
                    val = kv * wg;
                }
                vals[j] = f2bf(val);
            }
            uint4 o;
            o.x = (unsigned)vals[0] | ((unsigned)vals[1] << 16);
            o.y = (unsigned)vals[2] | ((unsigned)vals[3] << 16);
            o.z = (unsigned)vals[4] | ((unsigned)vals[5] << 16);
            o.w = (unsigned)vals[6] | ((unsigned)vals[7] << 16);
            reinterpret_cast<uint4*>(afrag)[f * 64 + l] = o;
        }
    }
}

// ---- Kernel C: MFMA Toeplitz conv + tree cascade (R17 verbatim: global af).
__global__ __launch_bounds__(512, 4) void conv_tree_k(
    const unsigned short* __restrict__ Yb,
    const unsigned int* __restrict__ afrag,
    const float* __restrict__ Vo,
    const float* __restrict__ C,
    const float* __restrict__ Theta,
    float* __restrict__ out)
{
    __shared__ __align__(16) unsigned short Yt[NJ * STR];  // 33856 B, col-major
    __shared__ float sub[TILE * SUBS];                     // 6400 B
    __shared__ float sTheta[M_DIM];
    __shared__ float sExpC[M_DIM];

    const int tid = threadIdx.x;
    const int t0  = blockIdx.x * TILE;

    if (tid < M_DIM) {
        sTheta[tid] = Theta[tid];
        sExpC[tid]  = __expf(C[tid]);
    }

    // --- stage Yb rows [t0-50, t0+126) transposed into Yt[col'][r] (bf16),
    //     col' = (c>>2) + 23*(c&3); row pairs packed into dwords. 88 pairs.
    {
        unsigned int* Yw = reinterpret_cast<unsigned int*>(Yt);
        for (int i = tid; i < 88 * 23; i += 512) {
            int rp = i / 23;
            int q  = i - rp * 23;
            int g0 = t0 - 50 + 2 * rp;
            ushort4 ra = make_ushort4(0, 0, 0, 0);
            ushort4 rb = make_ushort4(0, 0, 0, 0);
            if ((unsigned)g0       < (unsigned)T_DIM) ra = reinterpret_cast<const ushort4*>(Yb)[(size_t)g0 * 23 + q];
            if ((unsigned)(g0 + 1) < (unsigned)T_DIM) rb = reinterpret_cast<const ushort4*>(Yb)[(size_t)(g0 + 1) * 23 + q];
            Yw[(q     ) * 92 + rp] = (unsigned)ra.x | ((unsigned)rb.x << 16);
            Yw[(q + 23) * 92 + rp] = (unsigned)ra.y | ((unsigned)rb.y << 16);
            Yw[(q + 46) * 92 + rp] = (unsigned)ra.z | ((unsigned)rb.z << 16);
            Yw[(q + 69) * 92 + rp] = (unsigned)ra.w | ((unsigned)rb.w << 16);
        }
    }

    const int l    = tid & 63;
    const int wave = tid >> 6;            // 0..7
    const int dt   = (wave & 3) * 16;     // t-subtile
    const int nt   = wave >> 2;           // m-tile (0: m 0-15, 1: m 16-22)
    const int n    = l & 15;
    const int m    = nt * 16 + n;
    const bool mvalid = (m < M_DIM);
    const int mc   = mvalid ? m : 0;
    const int kq   = (l >> 4) << 3;       // k-slot base: 0,8,16,24

    __syncthreads();

    f32x4 acc = {0.f, 0.f, 0.f, 0.f};
    const uint4* AF = reinterpret_cast<const uint4*>(afrag);

    #pragma unroll
    for (int g = 0; g < 4; ++g) {
        // column j: j%23 == mc, j%4 == g -> a = 3*(g-mc) mod 4; col' = (j>>2) + 23g
        int a  = (3 * ((g - mc) & 3)) & 3;
        int j  = mc + 23 * a;
        int cp = (j >> 2) + 23 * g;
        const unsigned short* colp = &Yt[cp * STR + dt + kq];

        uint4 a0 = AF[(g * 4 + 0) * 64 + l];
        uint4 a1 = AF[(g * 4 + 1) * 64 + l];
        uint4 a2 = AF[(g * 4 + 2) * 64 + l];
        uint4 a3 = AF[(g * 4 + 3) * 64 + l];

        bf16x8 b0 = *reinterpret_cast<const bf16x8*>(colp);
        acc = __builtin_amdgcn_mfma_f32_16x16x32_bf16(__builtin_bit_cast(bf16x8, a0), b0, acc, 0, 0, 0);
        bf16x8 b1 = *reinterpret_cast<const bf16x8*>(colp + 32);
        acc = __builtin_amdgcn_mfma_f32_16x16x32_bf16(__builtin_bit_cast(bf16x8, a1), b1, acc, 0, 0, 0);
        bf16x8 b2 = *reinterpret_cast<const bf16x8*>(colp + 64);
        acc = __builtin_amdgcn_mfma_f32_16x16x32_bf16(__builtin_bit_cast(bf16x8, a2), b2, acc, 0, 0, 0);
        bf16x8 b3 = *reinterpret_cast<const bf16x8*>(colp + 96);
        acc = __builtin_amdgcn_mfma_f32_16x16x32_bf16(__builtin_bit_cast(bf16x8, a3), b3, acc, 0, 0, 0);
    }

    // epilogue: D col = l&15, row = (l>>4)*4 + r  ->  t_local = dt + row, m-col
    if (mvalid) {
        int i0 = (l >> 4) * 4;
        #pragma unroll
        for (int r = 0; r < 4; ++r)
            sub[(dt + i0 + r) * SUBS + m] = acc[r];
    }
    __syncthreads();

    // --- tree cascade, one thread per timestep
    if (tid < TILE) {
        int t = t0 + tid;
        if (t < T_DIM) {
            const float* s = &sub[tid * SUBS];
            float o[M_DIM];
            #pragma unroll
            for (int mm = 11; mm < 23; ++mm) {
                float x = s[mm] - sTheta[mm];
                o[mm] = sExpC[mm] / (1.f + __expf(-x));
            }
            #pragma unroll
            for (int rr = 10; rr >= 0; --rr) {
                float x = s[rr] + o[2 * rr + 1] + o[2 * rr + 2] - sTheta[rr];
                o[rr] = sExpC[rr] / (1.f + __expf(-x));
            }
            out[t] = o[0] + Vo[0];
        }
    }
}

extern "C" void kernel_launch(void* const* d_in, const int* in_sizes, int n_in,
                              void* d_out, int out_size, void* d_ws, size_t ws_size,
                              hipStream_t stream) {
    const float* X     = (const float*)d_in[0];
    const float* Vo    = (const float*)d_in[1];
    const float* Tau   = (const float*)d_in[2];
    const float* Delta = (const float*)d_in[3];
    const float* W     = (const float*)d_in[4];
    const float* C     = (const float*)d_in[5];
    const float* Theta = (const float*)d_in[6];
    float* out = (float*)d_out;

    unsigned short* Yb  = (unsigned short*)d_ws;                                  // 5.52 MB
    unsigned int* afrag = (unsigned int*)((char*)d_ws + (size_t)T_DIM * NJ * 2);  // 16 KB

    reduce_k<<<T_DIM / ROWS, 256, 0, stream>>>(X, Tau, Delta, W, Yb, afrag);
    conv_tree_k<<<(T_DIM + TILE - 1) / TILE, 512, 0, stream>>>(
        Yb, afrag, Vo, C, Theta, out);
}